// Round 1
// baseline (233.700 us; speedup 1.0000x reference)
//
#include <hip/hip_runtime.h>
#include <stdint.h>

#define SAMPLES   524288
#define BATCH     16
#define T_FRAMES  2048
#define K_FFT     1024
#define HOPSZ     256
#define CACHEPAD  1023
#define NCH       513        // output freq bins
#define NCH_PAD   576        // 9 * 64
#define M_FRAMES  (BATCH*T_FRAMES)   // 32768

typedef __bf16  bf16x8 __attribute__((ext_vector_type(8)));
typedef float   f32x4  __attribute__((ext_vector_type(4)));

__device__ __forceinline__ unsigned short f2bf(float f) {
    union { float f; unsigned u; } v; v.f = f;
    unsigned r = v.u + 0x7fffu + ((v.u >> 16) & 1u);   // round-to-nearest-even
    return (unsigned short)(r >> 16);
}

// ---------------- prep 1: im2col frame matrix, fp32 -> bf16 -------------
// F[m][k], m = b*2048 + t, value = x[b][t*HOP - 1023 + k] (0 if idx < 0)
__global__ void frames_prep(const float* __restrict__ x, unsigned short* __restrict__ F) {
    long long i = (long long)blockIdx.x * blockDim.x + threadIdx.x;  // pair index
    int k = ((int)(i & 511)) * 2;
    int m = (int)(i >> 9);
    if (m >= M_FRAMES) return;
    int t = m & (T_FRAMES - 1);
    int b = m >> 11;
    int pos = t * HOPSZ - CACHEPAD + k;
    const float* xb = x + (long long)b * SAMPLES;
    float v0 = (pos     >= 0) ? xb[pos]     : 0.f;
    float v1 = (pos + 1 >= 0) ? xb[pos + 1] : 0.f;
    unsigned packed = (unsigned)f2bf(v0) | ((unsigned)f2bf(v1) << 16);
    *(unsigned*)&F[(long long)m * K_FFT + k] = packed;
}

// ---------------- prep 2: weight fp32 -> bf16, pad 513 -> 576 rows ------
// Wb[sel][c][k], sel 0 = cos rows (weight rows 0..512), sel 1 = sin rows
// (weight rows 513..1025); rows 513..575 zero-padded.
__global__ void weight_prep(const float* __restrict__ w, unsigned short* __restrict__ Wb) {
    int i = blockIdx.x * blockDim.x + threadIdx.x;   // 2*576*1024 = 1179648 total
    int k = i & 1023;
    int c = (i >> 10) % NCH_PAD;
    int s = i / (NCH_PAD * 1024);
    if (s >= 2) return;
    float v = (c < NCH) ? w[((long long)(s * NCH + c)) * K_FFT + k] : 0.f;
    Wb[i] = f2bf(v);
}

// ---------------- async global -> LDS (16 B per lane) -------------------
__device__ __forceinline__ void gll16(const unsigned short* g, unsigned short* s) {
    __builtin_amdgcn_global_load_lds(
        (const __attribute__((address_space(1))) void*)g,
        (__attribute__((address_space(3))) void*)s,
        16, 0, 0);
}

// ---------------- main GEMM + magnitude epilogue ------------------------
// Block tile: 128 channel-rows (cos/sin interleaved per 16) x 128 frames.
// Ws row r -> sel = (r>>4)&1, ch_local = ((r>>5)<<4) | (r&15).
// 4 waves in 2x2: wave_m = w&1 (64 ch-rows), wave_n = w>>1 (64 frames).
__global__ __launch_bounds__(256, 2)
void stft_gemm(const unsigned short* __restrict__ F,
               const unsigned short* __restrict__ Wb,
               float* __restrict__ out) {
    __shared__ unsigned short Ws[128 * 32];
    __shared__ unsigned short Fs[128 * 32];

    const int nt  = blockIdx.x;   // 0..8 channel tile
    const int ft  = blockIdx.y;   // 0..255 frame tile
    const int tid = threadIdx.x;
    const int l   = tid & 63;
    const int w   = tid >> 6;
    const int ln  = l & 15;
    const int qd  = l >> 4;

    const int m0 = ft * 128;      // global frame base (tile never crosses a batch)

    // ---- staging source pointers (wave w stages rows w*32 .. w*32+31) ----
    const int row0 = w * 32 + (l >> 2);          // rows row0 and row0+16
    const unsigned short* fg0 = F + (long long)(m0 + row0) * K_FFT + (l & 3) * 8;
    const unsigned short* fg1 = fg0 + 16 * K_FFT;

    auto wrow_ptr = [&](int r) {
        int sel = (r >> 4) & 1;
        int chl = ((r >> 5) << 4) | (r & 15);
        int ch  = nt * 64 + chl;                 // < 576, zero-padded rows ok
        return Wb + ((long long)(sel * NCH_PAD + ch)) * K_FFT + (l & 3) * 8;
    };
    const unsigned short* wg0 = wrow_ptr(row0);
    const unsigned short* wg1 = wrow_ptr(row0 + 16);

    unsigned short* fs_dst0 = Fs + w * 1024;         // + lane*16B implicit
    unsigned short* fs_dst1 = Fs + w * 1024 + 512;
    unsigned short* ws_dst0 = Ws + w * 1024;
    unsigned short* ws_dst1 = Ws + w * 1024 + 512;

    const int wave_m = w & 1;
    const int wave_n = w >> 1;

    f32x4 acc[4][4];
    #pragma unroll
    for (int i = 0; i < 4; ++i)
        #pragma unroll
        for (int j = 0; j < 4; ++j)
            acc[i][j] = (f32x4){0.f, 0.f, 0.f, 0.f};

    int a_off[4], b_off[4];
    #pragma unroll
    for (int i = 0; i < 4; ++i) a_off[i] = (wave_m * 64 + i * 16 + ln) * 32 + qd * 8;
    #pragma unroll
    for (int j = 0; j < 4; ++j) b_off[j] = (wave_n * 64 + j * 16 + ln) * 32 + qd * 8;

    for (int kk = 0; kk < K_FFT; kk += 32) {
        gll16(fg0 + kk, fs_dst0);
        gll16(fg1 + kk, fs_dst1);
        gll16(wg0 + kk, ws_dst0);
        gll16(wg1 + kk, ws_dst1);
        __syncthreads();   // compiler emits vmcnt(0) drain before barrier

        bf16x8 av[4], bv[4];
        #pragma unroll
        for (int i = 0; i < 4; ++i) av[i] = *(const bf16x8*)&Ws[a_off[i]];
        #pragma unroll
        for (int j = 0; j < 4; ++j) bv[j] = *(const bf16x8*)&Fs[b_off[j]];

        #pragma unroll
        for (int i = 0; i < 4; ++i)
            #pragma unroll
            for (int j = 0; j < 4; ++j)
                acc[i][j] = __builtin_amdgcn_mfma_f32_16x16x32_bf16(av[i], bv[j], acc[i][j], 0, 0, 0);

        __syncthreads();
    }

    // ---- epilogue: mag = sqrt(max(re^2 + im^2, 1e-12)), coalesced stores ----
    // D layout (16x16x32): n = lane&15 (frame), m = qd*4 + reg (channel).
    // acc[2p] = cos block p, acc[2p+1] = sin block p (row interleave).
    const int b  = ft >> 4;
    const int t0 = (ft & 15) * 128;
    #pragma unroll
    for (int p = 0; p < 2; ++p) {
        #pragma unroll
        for (int j = 0; j < 4; ++j) {
            #pragma unroll
            for (int r = 0; r < 4; ++r) {
                float re  = acc[2 * p][j][r];
                float im  = acc[2 * p + 1][j][r];
                float mag = sqrtf(fmaxf(re * re + im * im, 1e-12f));
                int ch = nt * 64 + (wave_m * 2 + p) * 16 + qd * 4 + r;
                int t  = t0 + wave_n * 64 + j * 16 + ln;
                if (ch < NCH)
                    out[((long long)b * NCH + ch) * T_FRAMES + t] = mag;
            }
        }
    }
}

extern "C" void kernel_launch(void* const* d_in, const int* in_sizes, int n_in,
                              void* d_out, int out_size, void* d_ws, size_t ws_size,
                              hipStream_t stream) {
    const float* x  = (const float*)d_in[0];
    const float* wt = (const float*)d_in[1];
    float* out = (float*)d_out;

    unsigned short* F  = (unsigned short*)d_ws;                        // 64 MiB
    unsigned short* Wb = (unsigned short*)((char*)d_ws + (size_t)67108864); // 2.25 MiB

    frames_prep<<<65536, 256, 0, stream>>>(x, F);
    weight_prep<<<4608, 256, 0, stream>>>(wt, Wb);
    dim3 grid(9, 256);
    stft_gemm<<<grid, 256, 0, stream>>>(F, Wb, out);
}

// Round 2
// 199.297 us; speedup vs baseline: 1.1726x; 1.1726x over previous
//
#include <hip/hip_runtime.h>
#include <stdint.h>

#define SAMPLES   524288
#define BATCH     16
#define T_FRAMES  2048
#define K_FFT     1024
#define HOPSZ     256
#define CACHEPAD  1023
#define NCH       513                  // output freq bins
#define NCH_PAD   576                  // 9 * 64
#define XROW      525312               // 1023 zero-pad + 524288 samples + 1 spare

typedef __bf16          bf16x8 __attribute__((ext_vector_type(8)));
typedef float           f32x4  __attribute__((ext_vector_type(4)));
typedef unsigned short  u16x8  __attribute__((ext_vector_type(8)));

__device__ __forceinline__ unsigned short f2bf(float f) {
    union { float f; unsigned u; } v; v.f = f;
    unsigned r = v.u + 0x7fffu + ((v.u >> 16) & 1u);   // round-to-nearest-even
    return (unsigned short)(r >> 16);
}

// ---------- prep 1: x fp32 -> bf16 with 1023-zero left pad per batch ------
__global__ void x2bf(const float* __restrict__ x, unsigned short* __restrict__ Xb) {
    int bat = blockIdx.y;
    int e0 = (blockIdx.x * 256 + threadIdx.x) * 8;
    if (e0 >= XROW) return;
    const float* xb = x + (long long)bat * SAMPLES;
    u16x8 v;
    #pragma unroll
    for (int e = 0; e < 8; ++e) {
        int s = e0 + e - CACHEPAD;                      // sample index
        float f = (s >= 0 && s < SAMPLES) ? xb[s] : 0.f;
        v[e] = f2bf(f);
    }
    *(u16x8*)&Xb[(long long)bat * XROW + e0] = v;
}

// ---------- prep 2: weight fp32 -> bf16, pad 513 -> 576 rows per half -----
__global__ void weight_prep(const float* __restrict__ w, unsigned short* __restrict__ Wb) {
    int i = blockIdx.x * blockDim.x + threadIdx.x;     // 2*576*1024 total
    int k = i & 1023;
    int c = (i >> 10) % NCH_PAD;
    int s = i / (NCH_PAD * 1024);
    if (s >= 2) return;
    float v = (c < NCH) ? w[((long long)(s * NCH + c)) * K_FFT + k] : 0.f;
    Wb[i] = f2bf(v);
}

// ---------- async global -> LDS (16 B per lane, dst = base + lane*16) -----
__device__ __forceinline__ void gll16(const unsigned short* g, unsigned short* s) {
    __builtin_amdgcn_global_load_lds(
        (const __attribute__((address_space(1))) void*)g,
        (__attribute__((address_space(3))) void*)s,
        16, 0, 0);
}

// ---------- main GEMM + magnitude epilogue --------------------------------
// Block tile: 128 channel-rows (cos/sin interleaved per 16) x 128 frames,
// BK = 64, frames staged directly from padded bf16 x (im2col at stage time).
// LDS layout [row][64] with XOR column swizzle: LDS[r][chunk] holds global
// chunk (chunk ^ (r&7)) (chunks of 8 elems = 16 B).
__global__ __launch_bounds__(256, 3)
void stft_gemm(const unsigned short* __restrict__ Xb,
               const unsigned short* __restrict__ Wb,
               float* __restrict__ out) {
    __shared__ unsigned short Ws[128 * 64];   // 16 KB
    __shared__ unsigned short Fs[128 * 64];   // 16 KB

    const int nt  = blockIdx.x;   // 0..8  channel tile
    const int ft  = blockIdx.y;   // 0..255 frame tile
    const int tid = threadIdx.x;
    const int l   = tid & 63;
    const int w   = tid >> 6;
    const int ln  = l & 15;
    const int qd  = l >> 4;

    const int b  = ft >> 4;
    const int t0 = (ft & 15) * 128;            // frame tile never crosses a batch

    const unsigned short* xbase = Xb + (long long)b * XROW;

    // ---- staging: wave w stages rows [w*32, w*32+32) of Fs and Ws,
    //      4 gll16 calls each; call c: row = w*32 + c*8 + (l>>3),
    //      lds chunk = l&7 (implicit dst), global chunk = (l&7) ^ (row&7).
    const int srow   = l >> 3;
    const int schunk = l & 7;

    const unsigned short* fsrc[4];
    const unsigned short* wsrc[4];
    unsigned short* fdst[4];
    unsigned short* wdst[4];
    #pragma unroll
    for (int c = 0; c < 4; ++c) {
        int r = w * 32 + c * 8 + srow;
        int gchunk = schunk ^ (r & 7);
        fsrc[c] = xbase + (t0 + r) * HOPSZ + gchunk * 8;   // frame r, k-chunk
        int sel = (r >> 4) & 1;
        int chl = ((r >> 5) << 4) | (r & 15);
        int ch  = nt * 64 + chl;                           // < 576, pad rows = 0
        wsrc[c] = Wb + ((long long)(sel * NCH_PAD + ch)) * K_FFT + gchunk * 8;
        fdst[c] = Fs + (w * 32 + c * 8) * 64;
        wdst[c] = Ws + (w * 32 + c * 8) * 64;
    }

    const int wave_m = w & 1;
    const int wave_n = w >> 1;

    f32x4 acc[4][4];
    #pragma unroll
    for (int i = 0; i < 4; ++i)
        #pragma unroll
        for (int j = 0; j < 4; ++j)
            acc[i][j] = (f32x4){0.f, 0.f, 0.f, 0.f};

    // ds_read offsets: row = base + i*16 + ln (row&7 == ln&7);
    // global chunk wanted = k2*4 + qd -> lds chunk = (k2*4+qd) ^ (ln&7)
    int a_off[4][2], b_off[4][2];
    #pragma unroll
    for (int i = 0; i < 4; ++i)
        #pragma unroll
        for (int k2 = 0; k2 < 2; ++k2) {
            int ck = ((k2 * 4 + qd) ^ (ln & 7)) * 8;
            a_off[i][k2] = (wave_m * 64 + i * 16 + ln) * 64 + ck;
            b_off[i][k2] = (wave_n * 64 + i * 16 + ln) * 64 + ck;
        }

    for (int kk = 0; kk < K_FFT; kk += 64) {
        #pragma unroll
        for (int c = 0; c < 4; ++c) gll16(fsrc[c] + kk, fdst[c]);
        #pragma unroll
        for (int c = 0; c < 4; ++c) gll16(wsrc[c] + kk, wdst[c]);
        __syncthreads();

        #pragma unroll
        for (int k2 = 0; k2 < 2; ++k2) {
            bf16x8 av[4], bv[4];
            #pragma unroll
            for (int i = 0; i < 4; ++i) av[i] = *(const bf16x8*)&Ws[a_off[i][k2]];
            #pragma unroll
            for (int j = 0; j < 4; ++j) bv[j] = *(const bf16x8*)&Fs[b_off[j][k2]];
            #pragma unroll
            for (int i = 0; i < 4; ++i)
                #pragma unroll
                for (int j = 0; j < 4; ++j)
                    acc[i][j] = __builtin_amdgcn_mfma_f32_16x16x32_bf16(av[i], bv[j], acc[i][j], 0, 0, 0);
        }
        __syncthreads();
    }

    // ---- epilogue: mag = sqrt(max(re^2+im^2, 1e-12)), coalesced stores ----
    // D layout (16x16x32): frame = lane&15, channel-sub = qd*4 + reg.
    #pragma unroll
    for (int p = 0; p < 2; ++p) {
        #pragma unroll
        for (int j = 0; j < 4; ++j) {
            #pragma unroll
            for (int r = 0; r < 4; ++r) {
                float re  = acc[2 * p][j][r];
                float im  = acc[2 * p + 1][j][r];
                float mag = sqrtf(fmaxf(re * re + im * im, 1e-12f));
                int ch = nt * 64 + (wave_m * 2 + p) * 16 + qd * 4 + r;
                int t  = t0 + wave_n * 64 + j * 16 + ln;
                if (ch < NCH)
                    out[((long long)b * NCH + ch) * T_FRAMES + t] = mag;
            }
        }
    }
}

extern "C" void kernel_launch(void* const* d_in, const int* in_sizes, int n_in,
                              void* d_out, int out_size, void* d_ws, size_t ws_size,
                              hipStream_t stream) {
    const float* x  = (const float*)d_in[0];
    const float* wt = (const float*)d_in[1];
    float* out = (float*)d_out;

    unsigned short* Xb = (unsigned short*)d_ws;                          // 16.81 MiB
    unsigned short* Wb = (unsigned short*)((char*)d_ws + (size_t)33554432); // 2.25 MiB

    dim3 xgrid(257, 16);
    x2bf<<<xgrid, 256, 0, stream>>>(x, Xb);
    weight_prep<<<4608, 256, 0, stream>>>(wt, Wb);
    dim3 grid(9, 256);
    stft_gemm<<<grid, 256, 0, stream>>>(Xb, Wb, out);
}

// Round 3
// 162.438 us; speedup vs baseline: 1.4387x; 1.2269x over previous
//
#include <hip/hip_runtime.h>
#include <stdint.h>

#define SAMPLES   524288
#define BATCH     16
#define T_FRAMES  2048
#define K_FFT     1024
#define HOPSZ     256
#define CACHEPAD  1023
#define NCH       513                  // output freq bins
#define NCH_PAD   576                  // 9 * 64
#define XROW      525312               // 1023 zero-pad + 524288 samples + 1 spare (16B-aligned rows)

typedef __bf16          bf16x8 __attribute__((ext_vector_type(8)));
typedef float           f32x4  __attribute__((ext_vector_type(4)));
typedef unsigned short  u16x8  __attribute__((ext_vector_type(8)));

__device__ __forceinline__ unsigned short f2bf(float f) {
    union { float f; unsigned u; } v; v.f = f;
    unsigned r = v.u + 0x7fffu + ((v.u >> 16) & 1u);   // round-to-nearest-even
    return (unsigned short)(r >> 16);
}

// ---------- prep 1: x fp32 -> bf16 with 1023-zero left pad per batch ------
// Vectorized: float4 reads of x, scalar u16 stores (writes are cheap).
__global__ void x2bf(const float* __restrict__ x, unsigned short* __restrict__ Xb) {
    int bat = blockIdx.y;
    unsigned short* xbo = Xb + (long long)bat * XROW;
    if (blockIdx.x == 0) {                      // zero the pad region
        for (int j = threadIdx.x; j < CACHEPAD; j += 256) xbo[j] = 0;
        xbo[XROW - 1] = 0;
    }
    int i0 = (blockIdx.x * 256 + threadIdx.x) * 8;     // sample base, 8 per thread
    if (i0 >= SAMPLES) return;
    const float* xb = x + (long long)bat * SAMPLES;
    f32x4 a = *(const f32x4*)&xb[i0];
    f32x4 b = *(const f32x4*)&xb[i0 + 4];
    unsigned short* dst = xbo + CACHEPAD + i0;
    #pragma unroll
    for (int e = 0; e < 4; ++e) dst[e]     = f2bf(a[e]);
    #pragma unroll
    for (int e = 0; e < 4; ++e) dst[4 + e] = f2bf(b[e]);
}

// ---------- prep 2: weight fp32 -> bf16, pad 513 -> 576 rows per half -----
__global__ void weight_prep(const float* __restrict__ w, unsigned short* __restrict__ Wb) {
    int i = blockIdx.x * blockDim.x + threadIdx.x;     // 2*576*1024 total
    int k = i & 1023;
    int c = (i >> 10) % NCH_PAD;
    int s = i / (NCH_PAD * 1024);
    if (s >= 2) return;
    float v = (c < NCH) ? w[((long long)(s * NCH + c)) * K_FFT + k] : 0.f;
    Wb[i] = f2bf(v);
}

// ---------- async global -> LDS (16 B per lane, dst = base + lane*16) -----
__device__ __forceinline__ void gll16(const unsigned short* g, unsigned short* s) {
    __builtin_amdgcn_global_load_lds(
        (const __attribute__((address_space(1))) void*)g,
        (__attribute__((address_space(3))) void*)s,
        16, 0, 0);
}

// ---------- main GEMM + magnitude epilogue --------------------------------
// Block tile: 128 channel-rows (cos/sin interleaved per 16) x 128 frames,
// BK = 64, frames staged directly from padded bf16 x (im2col at stage time).
// LDS layout [row][64] with XOR column swizzle (chunk ^= row&7).
// XCD-aware swizzle: flat grid 2304; xcd = id&7 picks a fixed 32-ft stripe,
// so each XCD's L2 holds its x stripe (~2 MB) + the weights (2.25 MB) and
// gets near-100% staging hits.
__global__ __launch_bounds__(256, 3)
void stft_gemm(const unsigned short* __restrict__ Xb,
               const unsigned short* __restrict__ Wb,
               float* __restrict__ out) {
    __shared__ unsigned short Ws[128 * 64];   // 16 KB
    __shared__ unsigned short Fs[128 * 64];   // 16 KB

    const int id  = blockIdx.x;
    const int xcd = id & 7;
    const int idx = id >> 3;        // 0..287
    const int nt  = idx >> 5;       // 0..8  channel tile (32 consecutive blocks share it)
    const int ft  = (xcd << 5) | (idx & 31);   // 0..255 frame tile, striped per XCD

    const int tid = threadIdx.x;
    const int l   = tid & 63;
    const int w   = tid >> 6;
    const int ln  = l & 15;
    const int qd  = l >> 4;

    const int b  = ft >> 4;
    const int t0 = (ft & 15) * 128;            // frame tile never crosses a batch

    const unsigned short* xbase = Xb + (long long)b * XROW;

    // ---- staging: wave w stages rows [w*32, w*32+32) of Fs and Ws,
    //      4 gll16 calls each; call c: row = w*32 + c*8 + (l>>3),
    //      lds chunk = l&7 (implicit dst), global chunk = (l&7) ^ (row&7).
    const int srow   = l >> 3;
    const int schunk = l & 7;

    const unsigned short* fsrc[4];
    const unsigned short* wsrc[4];
    unsigned short* fdst[4];
    unsigned short* wdst[4];
    #pragma unroll
    for (int c = 0; c < 4; ++c) {
        int r = w * 32 + c * 8 + srow;
        int gchunk = schunk ^ (r & 7);
        fsrc[c] = xbase + (t0 + r) * HOPSZ + gchunk * 8;   // frame r, k-chunk
        int sel = (r >> 4) & 1;
        int chl = ((r >> 5) << 4) | (r & 15);
        int ch  = nt * 64 + chl;                           // < 576, pad rows = 0
        wsrc[c] = Wb + ((long long)(sel * NCH_PAD + ch)) * K_FFT + gchunk * 8;
        fdst[c] = Fs + (w * 32 + c * 8) * 64;
        wdst[c] = Ws + (w * 32 + c * 8) * 64;
    }

    const int wave_m = w & 1;
    const int wave_n = w >> 1;

    f32x4 acc[4][4];
    #pragma unroll
    for (int i = 0; i < 4; ++i)
        #pragma unroll
        for (int j = 0; j < 4; ++j)
            acc[i][j] = (f32x4){0.f, 0.f, 0.f, 0.f};

    // ds_read offsets: row = base + i*16 + ln (row&7 == ln&7);
    // global chunk wanted = k2*4 + qd -> lds chunk = (k2*4+qd) ^ (ln&7)
    int a_off[4][2], b_off[4][2];
    #pragma unroll
    for (int i = 0; i < 4; ++i)
        #pragma unroll
        for (int k2 = 0; k2 < 2; ++k2) {
            int ck = ((k2 * 4 + qd) ^ (ln & 7)) * 8;
            a_off[i][k2] = (wave_m * 64 + i * 16 + ln) * 64 + ck;
            b_off[i][k2] = (wave_n * 64 + i * 16 + ln) * 64 + ck;
        }

    for (int kk = 0; kk < K_FFT; kk += 64) {
        #pragma unroll
        for (int c = 0; c < 4; ++c) gll16(fsrc[c] + kk, fdst[c]);
        #pragma unroll
        for (int c = 0; c < 4; ++c) gll16(wsrc[c] + kk, wdst[c]);
        __syncthreads();

        #pragma unroll
        for (int k2 = 0; k2 < 2; ++k2) {
            bf16x8 av[4], bv[4];
            #pragma unroll
            for (int i = 0; i < 4; ++i) av[i] = *(const bf16x8*)&Ws[a_off[i][k2]];
            #pragma unroll
            for (int j = 0; j < 4; ++j) bv[j] = *(const bf16x8*)&Fs[b_off[j][k2]];
            #pragma unroll
            for (int i = 0; i < 4; ++i)
                #pragma unroll
                for (int j = 0; j < 4; ++j)
                    acc[i][j] = __builtin_amdgcn_mfma_f32_16x16x32_bf16(av[i], bv[j], acc[i][j], 0, 0, 0);
        }
        __syncthreads();
    }

    // ---- epilogue: mag = sqrt(max(re^2+im^2, 1e-12)), coalesced stores ----
    // D layout (16x16x32): frame = lane&15, channel-sub = qd*4 + reg.
    #pragma unroll
    for (int p = 0; p < 2; ++p) {
        #pragma unroll
        for (int j = 0; j < 4; ++j) {
            #pragma unroll
            for (int r = 0; r < 4; ++r) {
                float re  = acc[2 * p][j][r];
                float im  = acc[2 * p + 1][j][r];
                float mag = sqrtf(fmaxf(re * re + im * im, 1e-12f));
                int ch = nt * 64 + (wave_m * 2 + p) * 16 + qd * 4 + r;
                int t  = t0 + wave_n * 64 + j * 16 + ln;
                if (ch < NCH)
                    out[((long long)b * NCH + ch) * T_FRAMES + t] = mag;
            }
        }
    }
}

extern "C" void kernel_launch(void* const* d_in, const int* in_sizes, int n_in,
                              void* d_out, int out_size, void* d_ws, size_t ws_size,
                              hipStream_t stream) {
    const float* x  = (const float*)d_in[0];
    const float* wt = (const float*)d_in[1];
    float* out = (float*)d_out;

    unsigned short* Xb = (unsigned short*)d_ws;                          // 16.04 MiB (16 rows)
    unsigned short* Wb = (unsigned short*)((char*)d_ws + (size_t)33554432); // 2.25 MiB

    dim3 xgrid(SAMPLES / (256 * 8), 16);     // 256 x 16
    x2bf<<<xgrid, 256, 0, stream>>>(x, Xb);
    weight_prep<<<4608, 256, 0, stream>>>(wt, Wb);
    stft_gemm<<<dim3(2304), 256, 0, stream>>>(Xb, Wb, out);
}